// Round 1
// baseline (241.287 us; speedup 1.0000x reference)
//
#include <hip/hip_runtime.h>
#include <stdint.h>

// B=16 H=8 L=512 D=64; fp32 in/out. out = concat(output[128,512,64], attn[128,512,512]).
// Round-5: XCD-aware block swizzle. HW maps linear block id % 8 -> XCD; the old
// (8,128) x-major grid put the 8 q-tiles sharing one bh's K/V on 8 DIFFERENT XCDs
// (each XCD streamed all 32MB of K/V through its 4MB L2 -> 90MB HBM over-fetch).
// Remap so XCD k owns bh in [k*16,(k+1)*16): resident working set 8bh x 256KB = 2MB,
// fits L2; K/V staging loads become L2 hits.
#define Ln 512
#define Dn 64
#define BHn 128
#define AOFF ((size_t)BHn*Ln*Dn)

typedef __attribute__((ext_vector_type(8))) short short8;   // 8 bf16 (4 VGPRs)
typedef __attribute__((ext_vector_type(4))) float f32x4;
typedef __attribute__((ext_vector_type(4))) unsigned int u32x4;
typedef __attribute__((ext_vector_type(2))) unsigned int u32x2;

#define KSTR  72    // K LDS row stride (halves): 144B = 9*16B odd -> conflict-free b128
#define VTSTR 136   // Vt LDS row stride (halves): 272B = 17*16B odd
#define PSTRH 136   // P chunk row stride (halves), per-wave private region

__device__ __forceinline__ uint16_t f2bf(float f){
  uint32_t x = __float_as_uint(f);
  return (uint16_t)((x + 0x7FFFu + ((x>>16)&1u)) >> 16);   // RNE
}
__device__ __forceinline__ float bf2f(uint16_t u){ return __uint_as_float(((uint32_t)u)<<16); }
__device__ __forceinline__ uint32_t pack2(float a, float b){
  return (uint32_t)f2bf(a) | ((uint32_t)f2bf(b)<<16);
}

extern "C" __global__ __launch_bounds__(256, 2)
void attn_mfma(const float* __restrict__ qg, const float* __restrict__ kg,
               const float* __restrict__ vg, const float* __restrict__ mg,
               float* __restrict__ outg)
{
  // LDS map: [0,36864): QK phase KHI[128][72]+KLO[128][72] bf16
  //                     PV phase VT[64][136] bf16 (17408B) + 4x per-wave P chunk (4352B each)
  //          [36864,38912): CMV[512] fp32 column-mask terms
  __shared__ uint4 ldsraw[(36864 + 2048)/16];
  uint16_t* KHI = (uint16_t*)ldsraw;
  uint16_t* KLO = KHI + 128*KSTR;
  uint16_t* VT  = (uint16_t*)ldsraw;
  float*    CMV = (float*)((char*)ldsraw + 36864);

  const int t    = threadIdx.x;
  const int lane = t & 63;
  const int wv   = t >> 6;
  const int li   = lane & 15;      // C-layout col; S^T col = query index i
  const int lq   = lane >> 4;      // quad

  // ---- XCD-aware swizzle: lin%8 == XCD (x-major hw linearization).
  // XCD k gets lins {k, k+8, ...}; give it bh in [k*16, k*16+16), tile = j&7.
  const int lin = blockIdx.x + (blockIdx.y << 3);
  const int xcd = lin & 7;
  const int jj  = lin >> 3;                     // 0..127 per XCD
  const int bh  = (xcd << 4) + (jj >> 3);       // 16 bh per XCD
  const int b   = bh >> 3;
  const int i0  = (jj & 7)*64 + wv*16;          // wave's 16 query rows

  const size_t base = (size_t)bh*(Ln*Dn);
  const float* mrow = mg + b*Ln;

  uint16_t* PW = (uint16_t*)((char*)ldsraw + 17408 + wv*(16*PSTRH*2));  // private P chunk

  // ---- column-mask terms: sentinel -> 1e9, else value (0) ----
  {
    float m0 = mrow[t], m1 = mrow[t+256];
    CMV[t]     = (m0 < -9000.f) ? 1e9f : m0;
    CMV[t+256] = (m1 < -9000.f) ? 1e9f : m1;
  }

  // ---- Q fragments (used as B operand: lane li holds Q[i0+li][kt*32+lq*8+e]) ----
  short8 qhi[2], qlo[2];
  {
    const float* qrow = qg + base + (size_t)(i0 + li)*Dn;
    #pragma unroll
    for (int kt=0; kt<2; ++kt){
      const float* p = qrow + kt*32 + lq*8;
      f32x4 x0 = *(const f32x4*)p;
      f32x4 x1 = *(const f32x4*)(p+4);
      #pragma unroll
      for (int e=0; e<8; ++e){
        float x = (e<4) ? x0[e] : x1[e-4];
        uint16_t h = f2bf(x);
        qhi[kt][e] = (short)h;
        qlo[kt][e] = (short)f2bf(x - bf2f(h));
      }
    }
  }

  // ---- S^T accumulators: 32 j-tiles x f32x4; lane holds S^T[j=jt*16+lq*4+r][i=li] ----
  f32x4 acc[32];
  #pragma unroll
  for (int j=0; j<32; ++j) acc[j] = (f32x4)0.f;

  // ---- S^T = K Q^T: 4 chunks of 128 K-rows, bf16 hi/lo split (3 MFMAs) ----
  const int sj = t>>1, skh = t&1;
  #pragma unroll
  for (int c=0; c<4; ++c){
    __syncthreads();
    {
      const float* kr = kg + base + (size_t)(c*128 + sj)*Dn + skh*32;
      uint16_t* dhi = KHI + sj*KSTR + skh*32;
      uint16_t* dlo = KLO + sj*KSTR + skh*32;
      #pragma unroll
      for (int w2=0; w2<4; ++w2){
        f32x4 x0 = *(const f32x4*)(kr + w2*8);
        f32x4 x1 = *(const f32x4*)(kr + w2*8 + 4);
        uint32_t hw[4], lw[4];
        #pragma unroll
        for (int pi=0; pi<4; ++pi){
          float a0 = (pi<2) ? x0[pi*2]   : x1[(pi-2)*2];
          float a1 = (pi<2) ? x0[pi*2+1] : x1[(pi-2)*2+1];
          uint16_t h0 = f2bf(a0), h1 = f2bf(a1);
          hw[pi] = (uint32_t)h0 | ((uint32_t)h1<<16);
          lw[pi] = (uint32_t)f2bf(a0 - bf2f(h0)) | ((uint32_t)f2bf(a1 - bf2f(h1))<<16);
        }
        *(u32x4*)(dhi + w2*8) = (u32x4){hw[0],hw[1],hw[2],hw[3]};
        *(u32x4*)(dlo + w2*8) = (u32x4){lw[0],lw[1],lw[2],lw[3]};
      }
    }
    __syncthreads();
    #pragma unroll
    for (int jt=0; jt<8; ++jt){
      #pragma unroll
      for (int kt=0; kt<2; ++kt){
        const int off = (jt*16 + li)*KSTR + kt*32 + lq*8;   // K row = A operand (m=li)
        short8 kh = *(const short8*)(KHI + off);
        short8 kl = *(const short8*)(KLO + off);
        f32x4 A = acc[c*8+jt];
        A = __builtin_amdgcn_mfma_f32_16x16x32_bf16(kh, qhi[kt], A, 0,0,0);
        A = __builtin_amdgcn_mfma_f32_16x16x32_bf16(kl, qhi[kt], A, 0,0,0);
        A = __builtin_amdgcn_mfma_f32_16x16x32_bf16(kh, qlo[kt], A, 0,0,0);
        acc[c*8+jt] = A;
      }
    }
  }

  // ---- mask + softmax over j (per lane: own 128 j's, then quad-combine) ----
  {
    float mv = mrow[i0 + li];
    const float rmv = (mv < -9000.f) ? 1e9f : mv;
    #pragma unroll
    for (int jt=0; jt<32; ++jt){
      f32x4 cm = *(const f32x4*)(CMV + jt*16 + lq*4);
      #pragma unroll
      for (int r=0; r<4; ++r)
        acc[jt][r] = (acc[jt][r]*0.125f - rmv) - cm[r];   // fp32 rounding matches ref
    }
  }
  float mx = -3.4e38f;
  #pragma unroll
  for (int jt=0; jt<32; ++jt)
    #pragma unroll
    for (int r=0; r<4; ++r) mx = fmaxf(mx, acc[jt][r]);
  mx = fmaxf(mx, __shfl_xor(mx, 16));
  mx = fmaxf(mx, __shfl_xor(mx, 32));
  float sum = 0.f;
  #pragma unroll
  for (int jt=0; jt<32; ++jt)
    #pragma unroll
    for (int r=0; r<4; ++r){ float e = __expf(acc[jt][r]-mx); acc[jt][r] = e; sum += e; }
  sum += __shfl_xor(sum, 16);
  sum += __shfl_xor(sum, 32);
  const float inv = 1.0f/sum;

  // ---- normalize + write attn (float4 per tile: row i0+li, cols jt*16+lq*4..+3) ----
  {
    float* arow = outg + AOFF + (size_t)bh*Ln*Ln + (size_t)(i0+li)*Ln;
    #pragma unroll
    for (int jt=0; jt<32; ++jt){
      f32x4 p = acc[jt]*inv;
      acc[jt] = p;
      *(f32x4*)(arow + jt*16 + lq*4) = p;
    }
  }

  // ---- PV: O^T = V^T P^T; V^T staged in LDS, P^T chunks via private LDS ----
  f32x4 oacc[4];
  #pragma unroll
  for (int dt=0; dt<4; ++dt) oacc[dt] = (f32x4)0.f;

  #pragma unroll
  for (int c=0; c<4; ++c){
    __syncthreads();                   // prior chunk's VT reads done (c=0: K reads done)
    #pragma unroll
    for (int it=0; it<2; ++it){        // stage V^T chunk: 128 j x 64 d via 4x4 reg transpose
      const int j0 = (t>>4)*4 + it*64;
      const int d0 = (t&15)*4;
      const float* vr = vg + base + (size_t)(c*128 + j0)*Dn + d0;
      f32x4 r0 = *(const f32x4*)(vr);
      f32x4 r1 = *(const f32x4*)(vr + Dn);
      f32x4 r2 = *(const f32x4*)(vr + 2*Dn);
      f32x4 r3 = *(const f32x4*)(vr + 3*Dn);
      #pragma unroll
      for (int qd=0; qd<4; ++qd){
        u32x2 w; w.x = pack2(r0[qd], r1[qd]); w.y = pack2(r2[qd], r3[qd]);
        *(u32x2*)(VT + (d0+qd)*VTSTR + j0) = w;
      }
    }
    __syncthreads();
    // write P chunk rows (per-wave private; lane owns row li cols jtl*16+lq*4..+3)
    #pragma unroll
    for (int jtl=0; jtl<8; ++jtl){
      const f32x4 p = acc[c*8+jtl];
      u32x2 w; w.x = pack2(p[0], p[1]); w.y = pack2(p[2], p[3]);
      *(u32x2*)(PW + li*PSTRH + jtl*16 + lq*4) = w;
    }
    asm volatile("s_waitcnt lgkmcnt(0)" ::: "memory");   // P writes visible within wave
    #pragma unroll
    for (int c32=0; c32<4; ++c32){
      short8 pf = *(const short8*)(PW + li*PSTRH + c32*32 + lq*8);   // P^T B-frag
      #pragma unroll
      for (int dt=0; dt<4; ++dt){
        short8 vb = *(const short8*)(VT + (dt*16+li)*VTSTR + c32*32 + lq*8); // V^T A-frag
        oacc[dt] = __builtin_amdgcn_mfma_f32_16x16x32_bf16(vb, pf, oacc[dt], 0,0,0);
      }
    }
  }

  // ---- store O (O^T C-layout: lane holds O[i=li][d=dt*16+lq*4+r] -> float4) ----
  #pragma unroll
  for (int dt=0; dt<4; ++dt)
    *(f32x4*)(outg + base + (size_t)(i0+li)*Dn + dt*16 + lq*4) = oacc[dt];
}

extern "C" void kernel_launch(void* const* d_in, const int* in_sizes, int n_in,
                              void* d_out, int out_size, void* d_ws, size_t ws_size,
                              hipStream_t stream)
{
  (void)in_sizes; (void)n_in; (void)d_ws; (void)ws_size; (void)out_size;
  dim3 grid(Ln/64, BHn);            // 8 x 128 blocks, 256 thr (4 waves x 16 q-rows)
  attn_mfma<<<grid, 256, 0, stream>>>((const float*)d_in[0], (const float*)d_in[1],
                                      (const float*)d_in[2], (const float*)d_in[3],
                                      (float*)d_out);
}